// Round 4
// baseline (65.709 us; speedup 1.0000x reference)
//
#include <hip/hip_runtime.h>

// Problem constants
#define BB 16
#define CC 2048
#define HH 32
#define WW 32
#define HW 1024   // H*W
#define NP 64     // n_points

// prep tiling
#define PCH 32            // c-rows per prep block
#define NCH (CC/PCH)      // 64 chunks

// gemm tiling
#define KB 32             // spatial-k per gemm block
#define CT 32             // c per K-step
#define NSTEP (CC/CT)     // 64

typedef __bf16 bf16x8 __attribute__((ext_vector_type(8)));
typedef float  f32x4  __attribute__((ext_vector_type(4)));

__device__ __forceinline__ unsigned f2bf2(float lo, float hi) {
    // pack two fp32 -> two RNE bf16 in one u32
    unsigned a = __float_as_uint(lo);
    unsigned b = __float_as_uint(hi);
    a += 0x7fffu + ((a >> 16) & 1u);
    b += 0x7fffu + ((b >> 16) & 1u);
    return (a >> 16) | (b & 0xffff0000u);
}

// ws layout:
//   qbf: [BB][NP][CC] bf16          = 4 MiB  (gathered queries, bf16(fea) columns)
//   np2: [NCH][BB][HW] f32          = 4 MiB  (partial key sum-of-squares, non-atomic)
//   rn:  [BB][HW] f32               = 64 KiB (rsqrt of key norms^2)
//   dot: [BB][NP][HW] f32           = 4 MiB  (raw bf16-GEMM dot products)

// ---------------------------------------------------------------------------
// Kernel 1: coalesced fea scan. Per (b, 32-row c-chunk):
//   - exact fp32 ssq partials  -> np2[cch][b][k]   (plain coalesced stores)
//   - query extraction via LDS -> qbf[b][p][c]     (bf16, coalesced stores)
// grid = (NCH, BB), block = 256 (4 waves; wave = one c-row per phase)
// ---------------------------------------------------------------------------
__global__ __launch_bounds__(256) void prep_kernel(const float* __restrict__ fea,
                                                   const float* __restrict__ pl,
                                                   unsigned short* __restrict__ qbf,
                                                   float* __restrict__ np2) {
    int cch = blockIdx.x, b = blockIdx.y;
    int t = threadIdx.x, lane = t & 63, rr = t >> 6;

    // point index for p = lane (used in extraction)
    int ix = (int)(pl[2 * lane + 0] * WW); ix = min(max(ix, 0), WW - 1);
    int iy = (int)(pl[2 * lane + 1] * HH); iy = min(max(iy, 0), HH - 1);
    int kp = iy * WW + ix;

    __shared__ unsigned short buf[2][4][HW];     // 16 KiB, double-buffered 4-row bf16 tile
    __shared__ unsigned short ex[NP][PCH + 4];   // 4.5 KiB, extracted queries [p][c_local]

    float ssq[16];
#pragma unroll
    for (int i = 0; i < 16; ++i) ssq[i] = 0.f;

    const float* base = fea + ((size_t)b * CC + cch * PCH + rr) * HW + 4 * lane;

#pragma unroll
    for (int ph = 0; ph < PCH / 4; ++ph) {       // 8 phases x 4 rows
        float4 fv[4];
#pragma unroll
        for (int s = 0; s < 4; ++s)
            fv[s] = *(const float4*)(base + (size_t)(ph * 4) * HW + 256 * s);
#pragma unroll
        for (int s = 0; s < 4; ++s) {
            ssq[4 * s + 0] += fv[s].x * fv[s].x;
            ssq[4 * s + 1] += fv[s].y * fv[s].y;
            ssq[4 * s + 2] += fv[s].z * fv[s].z;
            ssq[4 * s + 3] += fv[s].w * fv[s].w;
            uint2 pk;
            pk.x = f2bf2(fv[s].x, fv[s].y);
            pk.y = f2bf2(fv[s].z, fv[s].w);
            *(uint2*)&buf[ph & 1][rr][4 * lane + 256 * s] = pk;
        }
        __syncthreads();
        // extraction: thread (rr, p=lane) pulls its point's column from row rr
        ex[lane][ph * 4 + rr] = buf[ph & 1][rr][kp];
        // no second barrier: next phase writes the OTHER buffer; 2-ahead writes
        // are fenced by the next iteration's barrier.
    }
    __syncthreads();

    // cross-wave ssq reduce, reusing buf as float red[4][HW] (exactly 16 KiB)
    float* red = (float*)buf;
#pragma unroll
    for (int s = 0; s < 4; ++s) {
        f32x4 v = {ssq[4 * s + 0], ssq[4 * s + 1], ssq[4 * s + 2], ssq[4 * s + 3]};
        *(f32x4*)&red[rr * HW + 4 * lane + 256 * s] = v;
    }
    __syncthreads();
    {
        int k0 = 4 * t;
        f32x4 r0 = *(f32x4*)&red[0 * HW + k0];
        f32x4 r1 = *(f32x4*)&red[1 * HW + k0];
        f32x4 r2 = *(f32x4*)&red[2 * HW + k0];
        f32x4 r3 = *(f32x4*)&red[3 * HW + k0];
        f32x4 sum = (r0 + r1) + (r2 + r3);
        *(f32x4*)&np2[((size_t)cch * BB + b) * HW + k0] = sum;
    }
    // qbf write: thread t -> p = t>>2, 8 c-values
    {
        int p = t >> 2, part = t & 3;
        uint2 lo = *(uint2*)&ex[p][8 * part];
        uint2 hi = *(uint2*)&ex[p][8 * part + 4];
        uint4 o = make_uint4(lo.x, lo.y, hi.x, hi.y);
        *(uint4*)&qbf[((size_t)b * NP + p) * CC + cch * PCH + 8 * part] = o;
    }
}

// ---------------------------------------------------------------------------
// Kernel 2: reduce np2 partials -> rn = rsqrt(sum).
// grid = (8, BB), block = 128; one k per thread, coalesced over cch partials.
// ---------------------------------------------------------------------------
__global__ __launch_bounds__(128) void nred_kernel(const float* __restrict__ np2,
                                                   float* __restrict__ rn) {
    int b = blockIdx.y;
    int k = blockIdx.x * 128 + threadIdx.x;
    float s = 0.f;
#pragma unroll 8
    for (int cch = 0; cch < NCH; ++cch)
        s += np2[((size_t)cch * BB + b) * HW + k];
    rn[(size_t)b * HW + k] = rsqrtf(s);
}

// ---------------------------------------------------------------------------
// Kernel 3: bf16 MFMA GEMM. dot[b][p][k] = sum_c q[p][c] * fea[c][k]
// fea re-read is L3-resident after prep's scan. LDS tile stored TRANSPOSED
// [k][c] so a B-fragment is one ds_read_b128; XOR-swizzled (c16 ^ ((k>>1)&3))
// on both write and read for conflict-free access. Single barrier per step,
// double-buffered, next step's global loads issued under current MFMA.
// grid = (HW/KB, BB), block = 256 (wave w owns p-rows [16w, 16w+16))
// ---------------------------------------------------------------------------
__global__ __launch_bounds__(256) void gemm_kernel(const float* __restrict__ fea,
                                                   const unsigned short* __restrict__ qbf,
                                                   float* __restrict__ dot) {
    // XCD-chunked swizzle: 512 blocks, give each XCD 64 consecutive ids
    int id = blockIdx.x + (int)gridDim.x * blockIdx.y;        // 0..511
    int sid = (id & 7) * 64 + (id >> 3);
    int kc = sid & 31, b = sid >> 5;

    int t = threadIdx.x, lane = t & 63, w = t >> 6;
    int p0 = 16 * w, k0 = KB * kc;
    int gi = lane >> 4, ii = lane & 15;

    __shared__ __align__(16) unsigned short btT[2][KB][CT];   // [k][c] bf16, 2 KiB/buf

    // ---- staging map: thread t -> k=sk, c-quad scg (4 c values) ----
    int sk = t & 31, scg = t >> 5;
    int swz16 = (scg >> 1) ^ ((sk >> 1) & 3);                 // 16B-block XOR swizzle
    unsigned short* wdst = &btT[0][sk][swz16 * 8 + (scg & 1) * 4];
    const float* gsrc = fea + ((size_t)b * CC + scg * 4) * HW + k0 + sk;

    // ---- A fragment: lane needs q[p0 + ii][s*CT + 8*gi + e] ----
    const unsigned short* arow = qbf + ((size_t)b * NP + p0 + ii) * CC + 8 * gi;

    // ---- B read base: row ii (kt=0), logical c-block gi, swizzled ----
    const unsigned short* brd = &btT[0][ii][(gi ^ ((ii >> 1) & 3)) * 8];

    f32x4 acc0 = {0.f, 0.f, 0.f, 0.f}, acc1 = {0.f, 0.f, 0.f, 0.f};
    union U8 { int4 i; bf16x8 v; };

    // preload step 0
    float g0 = gsrc[0 * HW], g1 = gsrc[1 * HW], g2 = gsrc[2 * HW], g3 = gsrc[3 * HW];
    U8 a_cur, a_nxt;
    a_cur.i = *(const int4*)arow;

    for (int s = 0; s < NSTEP; ++s) {
        int cur = s & 1;
        // stage current step (data loaded last iteration)
        uint2 pk;
        pk.x = f2bf2(g0, g1);
        pk.y = f2bf2(g2, g3);
        *(uint2*)(wdst + cur * (KB * CT)) = pk;
        __syncthreads();

        // prefetch next step (in flight under MFMA below)
        int sn = (s + 1 < NSTEP) ? s + 1 : s;
        const float* gs = gsrc + (size_t)sn * CT * HW;
        g0 = gs[0 * HW]; g1 = gs[1 * HW]; g2 = gs[2 * HW]; g3 = gs[3 * HW];
        a_nxt.i = *(const int4*)(arow + sn * CT);

        // compute: 2 B-frags (one ds_read_b128 each) + 2 MFMA
        const unsigned short* bp = brd + cur * (KB * CT);
        U8 b0, b1;
        b0.i = *(const int4*)bp;             // k-tile 0: rows ii
        b1.i = *(const int4*)(bp + 16 * CT); // k-tile 1: rows 16+ii (same swizzle)
        acc0 = __builtin_amdgcn_mfma_f32_16x16x32_bf16(a_cur.v, b0.v, acc0, 0, 0, 0);
        acc1 = __builtin_amdgcn_mfma_f32_16x16x32_bf16(a_cur.v, b1.v, acc1, 0, 0, 0);
        a_cur = a_nxt;
    }

    // D layout: col = lane&15 (k), row = 4*(lane>>4)+r (p)
    float* dbase = dot + ((size_t)b * NP) * HW;
#pragma unroll
    for (int r = 0; r < 4; ++r) {
        int p = p0 + 4 * gi + r;
        dbase[(size_t)p * HW + k0 + ii]      = acc0[r];
        dbase[(size_t)p * HW + k0 + 16 + ii] = acc1[r];
    }
}

// ---------------------------------------------------------------------------
// Kernel 4: finalize. val = dot * rn[k] * rn[kp]; min/max over k;
// out = valid ? (val - amin)/amax : 0.  grid = (NP, BB), block = 256.
// ---------------------------------------------------------------------------
__global__ __launch_bounds__(256) void finalize_kernel(const float* __restrict__ dot,
                                                       const float* __restrict__ rn,
                                                       const float* __restrict__ pl,
                                                       const int* __restrict__ valid,
                                                       float* __restrict__ out) {
    int p = blockIdx.x, b = blockIdx.y;
    int t = threadIdx.x;
    int k0 = 4 * t;

    int ix = (int)(pl[2 * p + 0] * WW); ix = min(max(ix, 0), WW - 1);
    int iy = (int)(pl[2 * p + 1] * HH); iy = min(max(iy, 0), HH - 1);
    int kp = iy * WW + ix;
    float rnp = rn[(size_t)b * HW + kp];

    float4 d  = *(const float4*)&dot[((size_t)b * NP + p) * HW + k0];
    float4 rk = *(const float4*)&rn[(size_t)b * HW + k0];

    float val[4];
    val[0] = d.x * rk.x * rnp;
    val[1] = d.y * rk.y * rnp;
    val[2] = d.z * rk.z * rnp;
    val[3] = d.w * rk.w * rnp;

    float mn = fminf(fminf(val[0], val[1]), fminf(val[2], val[3]));
    float mx = fmaxf(fmaxf(val[0], val[1]), fmaxf(val[2], val[3]));
#pragma unroll
    for (int off = 32; off; off >>= 1) {
        mn = fminf(mn, __shfl_xor(mn, off));
        mx = fmaxf(mx, __shfl_xor(mx, off));
    }
    __shared__ float smn[4], smx[4];
    int wave = t >> 6;
    if ((t & 63) == 0) { smn[wave] = mn; smx[wave] = mx; }
    __syncthreads();
    mn = fminf(fminf(smn[0], smn[1]), fminf(smn[2], smn[3]));
    mx = fmaxf(fmaxf(smx[0], smx[1]), fmaxf(smx[2], smx[3]));

    bool vld = valid[p] != 0;
    float4 o;
    o.x = vld ? (val[0] - mn) / mx : 0.f;
    o.y = vld ? (val[1] - mn) / mx : 0.f;
    o.z = vld ? (val[2] - mn) / mx : 0.f;
    o.w = vld ? (val[3] - mn) / mx : 0.f;
    *(float4*)&out[((size_t)b * NP + p) * HW + k0] = o;
}

// ---------------------------------------------------------------------------
extern "C" void kernel_launch(void* const* d_in, const int* in_sizes, int n_in,
                              void* d_out, int out_size, void* d_ws, size_t ws_size,
                              hipStream_t stream) {
    const float* fea = (const float*)d_in[0];
    const float* pl  = (const float*)d_in[1];
    const int* valid = (const int*)d_in[2];
    float* out = (float*)d_out;

    unsigned short* qbf = (unsigned short*)d_ws;                 // 4 MiB
    float* np2 = (float*)(qbf + (size_t)BB * NP * CC);           // 4 MiB
    float* rn  = np2 + (size_t)NCH * BB * HW;                    // 64 KiB
    float* dot = rn + (size_t)BB * HW;                           // 4 MiB

    prep_kernel<<<dim3(NCH, BB), 256, 0, stream>>>(fea, pl, qbf, np2);
    nred_kernel<<<dim3(8, BB), 128, 0, stream>>>(np2, rn);
    gemm_kernel<<<dim3(HW / KB, BB), 256, 0, stream>>>(fea, qbf, dot);
    finalize_kernel<<<dim3(NP, BB), 256, 0, stream>>>(dot, rn, pl, valid, out);
}